// Round 1
// baseline (157.064 us; speedup 1.0000x reference)
//
#include <hip/hip_runtime.h>

#define GFINE 128
#define GC 64
#define NCELLS (GC * GC * GC)   // 262144
#define CIN 32
#define COUT 64

// ---- Kernel A: scatter input rows into dense fine-grid + coarse occupancy flags ----
__global__ void scatter_kernel(const int* __restrict__ pos, int n,
                               int* __restrict__ idx_grid, int* __restrict__ flags) {
    int i = blockIdx.x * blockDim.x + threadIdx.x;
    if (i >= n) return;
    int x = pos[i * 3 + 0];
    int y = pos[i * 3 + 1];
    int z = pos[i * 3 + 2];
    idx_grid[(x * GFINE + y) * GFINE + z] = i;
    // benign race: all writers store 1
    flags[((x >> 1) * GC + (y >> 1)) * GC + (z >> 1)] = 1;
}

// ---- Kernel B1: per-1024-cell block exclusive scan of flags; emit block sums ----
__global__ void scan1_kernel(const int* __restrict__ flags, int* __restrict__ scan,
                             int* __restrict__ blockSums) {
    __shared__ int lds[256];
    int tid = threadIdx.x, bid = blockIdx.x;
    int4 v = ((const int4*)flags)[bid * 256 + tid];
    int s = v.x + v.y + v.z + v.w;
    lds[tid] = s;
    __syncthreads();
    for (int off = 1; off < 256; off <<= 1) {
        int t = (tid >= off) ? lds[tid - off] : 0;
        __syncthreads();
        lds[tid] += t;
        __syncthreads();
    }
    int incl = lds[tid];
    int excl = incl - s;
    int4 o;
    o.x = excl;
    o.y = excl + v.x;
    o.z = excl + v.x + v.y;
    o.w = excl + v.x + v.y + v.z;
    ((int4*)scan)[bid * 256 + tid] = o;
    if (tid == 255) blockSums[bid] = incl;
}

// ---- Kernel B2: exclusive scan of the 256 block sums, in place ----
__global__ void scan2_kernel(int* __restrict__ blockSums) {
    __shared__ int lds[256];
    int tid = threadIdx.x;
    int s = blockSums[tid];
    lds[tid] = s;
    __syncthreads();
    for (int off = 1; off < 256; off <<= 1) {
        int t = (tid >= off) ? lds[tid - off] : 0;
        __syncthreads();
        lds[tid] += t;
        __syncthreads();
    }
    blockSums[tid] = lds[tid] - s;   // exclusive
}

// ---- Kernel C: one wave per coarse cell; lane = output channel ----
__global__ void conv_kernel(const float* __restrict__ feat, const float* __restrict__ weight,
                            const int* __restrict__ idx_grid, const int* __restrict__ flags,
                            const int* __restrict__ scan, const int* __restrict__ blockSums,
                            float* __restrict__ out_feat, float* __restrict__ out_pos) {
    int gid = blockIdx.x * blockDim.x + threadIdx.x;
    int cell = gid >> 6;              // wave-uniform
    int lane = threadIdx.x & 63;
    if (!flags[cell]) return;
    int m = scan[cell] + blockSums[cell >> 10];
    int cx = cell >> 12, cy = (cell >> 6) & 63, cz = cell & 63;
    int fb = ((cx * 2) * GFINE + cy * 2) * GFINE + cz * 2;
    float acc = 0.f;
#pragma unroll
    for (int k = 0; k < 8; ++k) {
        int ox = k >> 2, oy = (k >> 1) & 1, oz = k & 1;
        int r = idx_grid[fb + ox * GFINE * GFINE + oy * GFINE + oz];
        r = __builtin_amdgcn_readfirstlane(r);   // wave-uniform -> force SGPR (scalar loads)
        if (r >= 0) {
            const float* __restrict__ frow = feat + (size_t)r * CIN;
            const float* __restrict__ wk = weight + k * CIN * COUT;
#pragma unroll
            for (int c = 0; c < CIN; ++c)
                acc = fmaf(frow[c], wk[c * COUT + lane], acc);
        }
    }
    out_feat[(size_t)m * COUT + lane] = acc;
    if (lane == 0) {
        out_pos[m * 3 + 0] = cx + 0.25f;
        out_pos[m * 3 + 1] = cy + 0.25f;
        out_pos[m * 3 + 2] = cz + 0.25f;
    }
}

extern "C" void kernel_launch(void* const* d_in, const int* in_sizes, int n_in,
                              void* d_out, int out_size, void* d_ws, size_t ws_size,
                              hipStream_t stream) {
    const float* feat   = (const float*)d_in[0];
    const int*   pos    = (const int*)d_in[1];
    const float* weight = (const float*)d_in[2];
    int n = in_sizes[1] / 3;
    int M = out_size / 67;   // out_feat M*64 + out_pos M*3

    char* ws = (char*)d_ws;
    int* idx_grid  = (int*)(ws);                                   // 128^3 * 4 = 8 MB
    int* flags     = (int*)(ws + (size_t)8388608);                 // 64^3  * 4 = 1 MB
    int* scan      = (int*)(ws + (size_t)8388608 + 1048576);       // 1 MB
    int* blockSums = (int*)(ws + (size_t)8388608 + 2097152);       // 1 KB

    hipMemsetAsync(idx_grid, 0xFF, (size_t)GFINE * GFINE * GFINE * 4, stream); // -1
    hipMemsetAsync(flags, 0, (size_t)NCELLS * 4, stream);

    scatter_kernel<<<(n + 255) / 256, 256, 0, stream>>>(pos, n, idx_grid, flags);
    scan1_kernel<<<256, 256, 0, stream>>>(flags, scan, blockSums);
    scan2_kernel<<<1, 256, 0, stream>>>(blockSums);

    float* out_feat = (float*)d_out;
    float* out_pos  = (float*)d_out + (size_t)M * COUT;
    conv_kernel<<<NCELLS / 4, 256, 0, stream>>>(feat, weight, idx_grid, flags, scan,
                                                blockSums, out_feat, out_pos);
}

// Round 2
// 90.069 us; speedup vs baseline: 1.7438x; 1.7438x over previous
//
#include <hip/hip_runtime.h>

#define GFINE 128
#define GC 64
#define NCELLS (GC * GC * GC)   // 262144
#define CIN 32
#define COUT 64
#define CPW 32                  // cells (output rows) per wave

// ---- Kernel A: scatter input rows into dense fine-grid + coarse occupancy flags ----
__global__ void scatter_kernel(const int* __restrict__ pos, int n,
                               int* __restrict__ idx_grid, int* __restrict__ flags) {
    int i = blockIdx.x * blockDim.x + threadIdx.x;
    if (i >= n) return;
    int x = pos[i * 3 + 0];
    int y = pos[i * 3 + 1];
    int z = pos[i * 3 + 2];
    idx_grid[(x * GFINE + y) * GFINE + z] = i;
    flags[((x >> 1) * GC + (y >> 1)) * GC + (z >> 1)] = 1;   // benign race
}

// ---- Kernel B1: per-1024-cell block exclusive scan of flags; emit block sums ----
__global__ void scan1_kernel(const int* __restrict__ flags, int* __restrict__ scan,
                             int* __restrict__ blockSums) {
    __shared__ int lds[256];
    int tid = threadIdx.x, bid = blockIdx.x;
    int4 v = ((const int4*)flags)[bid * 256 + tid];
    int s = v.x + v.y + v.z + v.w;
    lds[tid] = s;
    __syncthreads();
    for (int off = 1; off < 256; off <<= 1) {
        int t = (tid >= off) ? lds[tid - off] : 0;
        __syncthreads();
        lds[tid] += t;
        __syncthreads();
    }
    int incl = lds[tid];
    int excl = incl - s;
    int4 o;
    o.x = excl;
    o.y = excl + v.x;
    o.z = excl + v.x + v.y;
    o.w = excl + v.x + v.y + v.z;
    ((int4*)scan)[bid * 256 + tid] = o;
    if (tid == 255) blockSums[bid] = incl;
}

// ---- Kernel B2: exclusive scan of the 256 block sums; total M at blockSums[256] ----
__global__ void scan2_kernel(int* __restrict__ blockSums) {
    __shared__ int lds[256];
    int tid = threadIdx.x;
    int s = blockSums[tid];
    lds[tid] = s;
    __syncthreads();
    for (int off = 1; off < 256; off <<= 1) {
        int t = (tid >= off) ? lds[tid - off] : 0;
        __syncthreads();
        lds[tid] += t;
        __syncthreads();
    }
    blockSums[tid] = lds[tid] - s;   // exclusive
    if (tid == 255) blockSums[256] = lds[255];   // total occupied-cell count M
}

// ---- Kernel B3: compact occupied cells into rank-ordered list; write out_pos ----
__global__ void compact_kernel(const int* __restrict__ flags, const int* __restrict__ scan,
                               const int* __restrict__ blockSums,
                               int* __restrict__ cellList, float* __restrict__ out_pos) {
    int cell = blockIdx.x * blockDim.x + threadIdx.x;
    if (cell >= NCELLS) return;
    if (!flags[cell]) return;
    int m = scan[cell] + blockSums[cell >> 10];
    cellList[m] = cell;
    int cx = cell >> 12, cy = (cell >> 6) & 63, cz = cell & 63;
    out_pos[m * 3 + 0] = cx + 0.25f;
    out_pos[m * 3 + 1] = cy + 0.25f;
    out_pos[m * 3 + 2] = cz + 0.25f;
}

// ---- Kernel C: one wave per 32 output cells; lane = output channel ----
// Per wave: gather 32x8 tap indices with 4 vector loads, ballot -> per-tap hit
// masks, hold tap-k weights in 32 VGPRs, iterate only hits, accumulate in LDS.
__global__ __launch_bounds__(256) void conv2_kernel(
    const float* __restrict__ feat, const float* __restrict__ weight,
    const int* __restrict__ idx_grid, const int* __restrict__ cellList,
    const int* __restrict__ dM, float* __restrict__ out_feat) {
    __shared__ float lacc[4][CPW][COUT];   // 32 KB/block, per-wave disjoint
    const int lane = threadIdx.x & 63;
    const int wv = threadIdx.x >> 6;
    const int wid = blockIdx.x * 4 + wv;
    const int M = dM[0];
    const int base = wid * CPW;
    if (base >= M) return;
    int nj = M - base;
    if (nj > CPW) nj = CPW;

    float* la = &lacc[wv][0][0];
#pragma unroll
    for (int j = 0; j < CPW; ++j) la[j * COUT + lane] = 0.f;

    // lane l handles cell-slot (l&31); both halves duplicate the cell load
    const int l31 = lane & 31;
    int rank = base + l31;
    int cell = (rank < M) ? cellList[rank] : 0;   // clamp: garbage ranks -> safe addr
    int cx = cell >> 12, cy = (cell >> 6) & 63, cz = cell & 63;
    int vfb = ((cx * 2) * GFINE + cy * 2) * GFINE + cz * 2;

    // gather all 32x8 tap indices: load L covers taps 2L (lanes 0-31), 2L+1 (lanes 32-63)
    int vr[4];
    unsigned maskk[8];
    const int hi = lane >> 5;
#pragma unroll
    for (int L = 0; L < 4; ++L) {
        int k = 2 * L + hi;
        int off = (k >> 2) * (GFINE * GFINE) + (((k >> 1) & 1) * GFINE) + (k & 1);
        vr[L] = idx_grid[vfb + off];
        unsigned long long b = __ballot(vr[L] >= 0);
        maskk[2 * L]     = (unsigned)(b & 0xffffffffull);
        maskk[2 * L + 1] = (unsigned)(b >> 32);
    }
    const unsigned valid = (nj >= 32) ? 0xffffffffu : ((1u << nj) - 1u);

#pragma unroll
    for (int k = 0; k < 8; ++k) {
        unsigned mk = maskk[k] & valid;
        if (mk == 0) continue;
        // tap-k weights resident in VGPRs, amortized over up to 32 cells
        float wreg[CIN];
#pragma unroll
        for (int c = 0; c < CIN; ++c) wreg[c] = weight[(k * CIN + c) * COUT + lane];
        do {
            int j = (int)__builtin_ctz(mk);
            mk &= mk - 1;
            int r = __builtin_amdgcn_readlane(vr[k >> 1], j + (k & 1) * 32);  // SGPR
            const float4* f4 = (const float4*)(feat + (size_t)r * CIN);       // uniform addr
            float s0 = 0.f, s1 = 0.f, s2 = 0.f, s3 = 0.f;
#pragma unroll
            for (int q = 0; q < 8; ++q) {
                float4 a = f4[q];
                s0 = fmaf(a.x, wreg[4 * q + 0], s0);
                s1 = fmaf(a.y, wreg[4 * q + 1], s1);
                s2 = fmaf(a.z, wreg[4 * q + 2], s2);
                s3 = fmaf(a.w, wreg[4 * q + 3], s3);
            }
            la[j * COUT + lane] += (s0 + s1) + (s2 + s3);
        } while (mk != 0);
    }

#pragma unroll
    for (int j = 0; j < CPW; ++j)
        if (j < nj)
            out_feat[(size_t)(base + j) * COUT + lane] = la[j * COUT + lane];
}

extern "C" void kernel_launch(void* const* d_in, const int* in_sizes, int n_in,
                              void* d_out, int out_size, void* d_ws, size_t ws_size,
                              hipStream_t stream) {
    const float* feat   = (const float*)d_in[0];
    const int*   pos    = (const int*)d_in[1];
    const float* weight = (const float*)d_in[2];
    int n = in_sizes[1] / 3;
    int M = out_size / 67;   // out_feat M*64 + out_pos M*3

    char* ws = (char*)d_ws;
    int* idx_grid  = (int*)(ws);                                   // 8 MB
    int* flags     = (int*)(ws + (size_t)8388608);                 // 1 MB
    int* scan      = (int*)(ws + (size_t)8388608 + 1048576);       // 1 MB
    int* blockSums = (int*)(ws + (size_t)8388608 + 2097152);       // 257 ints
    int* cellList  = (int*)(ws + (size_t)8388608 + 2097152 + 4096);// 1 MB

    hipMemsetAsync(idx_grid, 0xFF, (size_t)GFINE * GFINE * GFINE * 4, stream); // -1
    hipMemsetAsync(flags, 0, (size_t)NCELLS * 4, stream);

    scatter_kernel<<<(n + 255) / 256, 256, 0, stream>>>(pos, n, idx_grid, flags);
    scan1_kernel<<<256, 256, 0, stream>>>(flags, scan, blockSums);
    scan2_kernel<<<1, 256, 0, stream>>>(blockSums);

    float* out_feat = (float*)d_out;
    float* out_pos  = (float*)d_out + (size_t)M * COUT;
    compact_kernel<<<NCELLS / 256, 256, 0, stream>>>(flags, scan, blockSums,
                                                     cellList, out_pos);

    const int* dM = blockSums + 256;
    conv2_kernel<<<NCELLS / (CPW * 4), 256, 0, stream>>>(feat, weight, idx_grid,
                                                         cellList, dM, out_feat);
}